// Round 8
// baseline (307.007 us; speedup 1.0000x reference)
//
#include <hip/hip_runtime.h>
#include <cstdint>
#include <cstddef>

#define NTH 256
#define NGT 128
#define BATCH 16
#define NC 80
#define G 16                  // GTs per chunk
#define NCHUNK (NGT / G)      // 8
#define NCHUNKS_TOTAL (3 * BATCH * NCHUNK)   // 384
#define HW0 25600
#define HW1 6400
#define HW2 1600
#define SL0 8                 // hw slices per level (seg: 3200/3200/1600)
#define SL1 2
#define SL2 1
#define MAXSL 8
#define NB0 (BATCH * NCHUNK * SL0)   // 1024
#define NB1 (BATCH * NCHUNK * SL1)   //  256
#define NB2 (BATCH * NCHUNK * SL2)   //  128
#define GRID (NB0 + NB1 + NB2)       // 1408 blocks = 5632 waves, all co-resident

// ws layout (bytes)
#define CNT_OFF    0                                       // cnt[384] + done
#define CNT_BYTES  ((NCHUNKS_TOTAL + 1) * (int)sizeof(unsigned int))
#define PART_OFF   4096
#define PART_BYTES (3 * BATCH * NGT * MAXSL * 8)           // 393,216
#define PARTL_OFF  (PART_OFF + PART_BYTES)

__device__ __forceinline__ unsigned long long umin64(unsigned long long a, unsigned long long b) {
    return a < b ? a : b;
}

#define EVAL(px, py, idx_) do {                                                   \
    _Pragma("unroll")                                                             \
    for (int g = 0; g < G; ++g) {                                                 \
        float dx = gx[g] - (px), dy = gy[g] - (py);                               \
        float d2 = dx * dx + dy * dy;                                             \
        unsigned long long key =                                                  \
            ((unsigned long long)__float_as_uint(d2) << 32) | (unsigned)(idx_);   \
        kmin[g] = umin64(kmin[g], key);                                           \
    } } while (0)

// Single fused kernel (R8): scan -> per-chunk loss -> final reduce, one
// dispatch. Cascade via counters sized for contention: 1408 adds spread over
// 384 per-chunk counters (<=8 each, negligible serialization — R5's failure
// was 1536 adds on ONE counter = ~20us tail), then 384 adds on one 'done'
// counter, staggered by loss compute. No spinning; dispatch-order
// independent; rocPRIM-style release/acquire __threadfence (R5 proved the
// pattern correct on this chip, just mis-sized).
// u64 key (d2 bits << 32 | idx): min == min-d2 with first-index tie-break,
// exactly matching jnp.argmin (d2 >= 0 so float bits monotone unsigned).
__global__ __launch_bounds__(NTH) void mega_kernel(
    const float* __restrict__ cls0, const float* __restrict__ cls1, const float* __restrict__ cls2,
    const float* __restrict__ reg0, const float* __restrict__ reg1, const float* __restrict__ reg2,
    const float* __restrict__ gt_boxes, const int* __restrict__ gt_labels,
    unsigned int* __restrict__ cnt,          // [384] chunk arrival counters
    unsigned int* __restrict__ done,         // [1] chunk-loss completion counter
    unsigned long long* __restrict__ part,   // [384*16*MAXSL] slice-partial keys
    float* __restrict__ partl,               // [384*3] per-chunk loss triples
    float* __restrict__ out)
{
    int x = blockIdx.x;
    int lvl, b, slice, chunk, HW, nsl;
    const float4* src4;
    const float* cls; const float* reg;
    if (x < NB0) {
        lvl = 0; b = x / (NCHUNK * SL0);
        int r = x % (NCHUNK * SL0);
        chunk = r % NCHUNK; slice = r / NCHUNK;
        HW = HW0; nsl = SL0; reg = reg0; cls = cls0;
    } else if (x < NB0 + NB1) {
        int y = x - NB0;
        lvl = 1; b = y / (NCHUNK * SL1);
        int r = y % (NCHUNK * SL1);
        chunk = r % NCHUNK; slice = r / NCHUNK;
        HW = HW1; nsl = SL1; reg = reg1; cls = cls1;
    } else {
        int y = x - NB0 - NB1;
        lvl = 2; b = y / NCHUNK; chunk = y % NCHUNK; slice = 0;
        HW = HW2; nsl = SL2; reg = reg2; cls = cls2;
    }
    src4 = reinterpret_cast<const float4*>(reg);

    const int seg = HW / nsl;
    const int e0 = slice * seg, e1 = e0 + seg;
    const int tid = threadIdx.x, wave = tid >> 6, lane = tid & 63;
    const int n0 = chunk * G;
    const int cg = (lvl * BATCH + b) * NCHUNK + chunk;   // chunk-global id [0,384)

    // ---- Phase 1: scan this hw slice for 16 GTs ----
    float gx[G], gy[G];   // block-uniform -> SGPRs (R7: VGPR_Count 52)
#pragma unroll
    for (int g = 0; g < G; ++g) {
        const float* gb = gt_boxes + (size_t)(b * NGT + n0 + g) * 4;
        gx[g] = gb[0]; gy[g] = gb[1];
    }

    unsigned long long kmin[G];
#pragma unroll
    for (int g = 0; g < G; ++g) kmin[g] = ~0ull;

    const float4* base = src4 + (size_t)b * HW;
    for (int i = e0 + tid; i < e1; i += NTH) {
        float4 p = base[i];
        EVAL(p.x, p.y, i);
    }

#pragma unroll
    for (int g = 0; g < G; ++g) {
#pragma unroll
        for (int off = 32; off >= 1; off >>= 1) {
            unsigned long long o = __shfl_down(kmin[g], off, 64);
            kmin[g] = umin64(kmin[g], o);
        }
    }

    __shared__ unsigned long long smem[G][4];
    if (lane == 0) {
#pragma unroll
        for (int g = 0; g < G; ++g) smem[g][wave] = kmin[g];
    }
    __syncthreads();

    if (tid < G) {
        unsigned long long key = umin64(umin64(smem[tid][0], smem[tid][1]),
                                        umin64(smem[tid][2], smem[tid][3]));
        part[((size_t)(lvl * BATCH + b) * NGT + n0 + tid) * MAXSL + slice] = key;
    }
    __syncthreads();   // all part stores issued & waited (vmcnt drain at barrier)

    // ---- Cascade gate 1: last slice-block of this chunk does the loss ----
    __shared__ int lastf;
    if (tid == 0) {
        __threadfence();                               // release part[] device-wide
        unsigned int old = atomicAdd(&cnt[cg], 1u);    // <=8-way contention
        lastf = (old == (unsigned)(nsl - 1));
    }
    __syncthreads();
    if (!lastf) return;

    // ---- Phase 2: loss for this chunk's 16 GTs ----
    __threadfence();                                   // acquire others' part[]
    __shared__ unsigned long long keyf[G];
    if (tid < G) {
        const unsigned long long* p =
            part + ((size_t)(lvl * BATCH + b) * NGT + n0 + tid) * MAXSL;
        unsigned long long k = p[0];
        for (int s = 1; s < nsl; ++s) k = umin64(k, p[s]);
        keyf[tid] = k;
    }
    __syncthreads();

    float ce_acc = 0.0f, l1_acc = 0.0f, w_acc = 0.0f;
#pragma unroll
    for (int j = 0; j < 4; ++j) {
        const int g = wave * 4 + j;
        unsigned long long key = keyf[g];
        int match = (int)(unsigned)(key & 0xffffffffu);
        float d2min = __uint_as_float((unsigned)(key >> 32));
        if (!(d2min < 6.25f)) continue;                // wave-uniform branch

        const int n = n0 + g;
        const int label = gt_labels[b * NGT + n];
        const float* c = cls + ((size_t)b * HW + match) * NC;

        float x1 = c[lane];
        float x2 = (lane < NC - 64) ? c[64 + lane] : -INFINITY;
        float mx = fmaxf(x1, x2);
#pragma unroll
        for (int off = 32; off >= 1; off >>= 1) mx = fmaxf(mx, __shfl_xor(mx, off, 64));
        float s = expf(x1 - mx) + ((lane < NC - 64) ? expf(x2 - mx) : 0.0f);
#pragma unroll
        for (int off = 32; off >= 1; off >>= 1) s += __shfl_xor(s, off, 64);

        if (lane == 0) {
            ce_acc += -(c[label] - mx - logf(s));
            const float* gb = gt_boxes + (size_t)(b * NGT + n) * 4;
            const float* gr = reg + ((size_t)b * HW + match) * 4;
            l1_acc += fabsf(gr[0] - gb[0]) + fabsf(gr[1] - gb[1]) +
                      fabsf(gr[2] - gb[2]) + fabsf(gr[3] - gb[3]);
            w_acc += 1.0f;
        }
    }

    __shared__ float cw[4][3];
    if (lane == 0) { cw[wave][0] = ce_acc; cw[wave][1] = l1_acc; cw[wave][2] = w_acc; }
    __syncthreads();

    // ---- Cascade gate 2: 384th chunk-finisher reduces & writes out ----
    __shared__ int finalf;
    if (tid == 0) {
        float* o = partl + (size_t)cg * 3;
        o[0] = cw[0][0] + cw[1][0] + cw[2][0] + cw[3][0];
        o[1] = cw[0][1] + cw[1][1] + cw[2][1] + cw[3][1];
        o[2] = cw[0][2] + cw[1][2] + cw[2][2] + cw[3][2];
        __threadfence();                               // release partl triple
        unsigned int old = atomicAdd(done, 1u);        // 384 staggered adds
        finalf = (old == (unsigned)(NCHUNKS_TOTAL - 1));
    }
    __syncthreads();
    if (!finalf) return;

    // ---- Phase 3: deterministic tree reduction of 384 triples ----
    __threadfence();                                   // acquire all partl
    float ce = 0.0f, l1 = 0.0f, w = 0.0f;
    for (int i = tid; i < NCHUNKS_TOTAL; i += NTH) {
        ce += partl[(size_t)i * 3 + 0];
        l1 += partl[(size_t)i * 3 + 1];
        w  += partl[(size_t)i * 3 + 2];
    }
#pragma unroll
    for (int off = 32; off >= 1; off >>= 1) {
        ce += __shfl_xor(ce, off, 64);
        l1 += __shfl_xor(l1, off, 64);
        w  += __shfl_xor(w,  off, 64);
    }
    __shared__ float sm[3][4];
    if (lane == 0) { sm[0][wave] = ce; sm[1][wave] = l1; sm[2][wave] = w; }
    __syncthreads();
    if (tid == 0) {
        float tce = sm[0][0] + sm[0][1] + sm[0][2] + sm[0][3];
        float tl1 = sm[1][0] + sm[1][1] + sm[1][2] + sm[1][3];
        float tw  = sm[2][0] + sm[2][1] + sm[2][2] + sm[2][3];
        float denom = fmaxf(tw, 1.0f);
        out[0] = tce / denom;
        out[1] = tl1 / denom;
        out[2] = tw;
    }
}

extern "C" void kernel_launch(void* const* d_in, const int* in_sizes, int n_in,
                              void* d_out, int out_size, void* d_ws, size_t ws_size,
                              hipStream_t stream) {
    // Map inputs BY SIZE (dict order interleaves cls/reg; all sizes distinct).
    const float* cls0 = nullptr; const float* cls1 = nullptr; const float* cls2 = nullptr;
    const float* reg0 = nullptr; const float* reg1 = nullptr; const float* reg2 = nullptr;
    const float* gt_boxes = nullptr; const int* gt_labels = nullptr;
    for (int i = 0; i < n_in; ++i) {
        switch (in_sizes[i]) {
            case BATCH * HW0 * NC: cls0 = (const float*)d_in[i]; break;
            case BATCH * HW1 * NC: cls1 = (const float*)d_in[i]; break;
            case BATCH * HW2 * NC: cls2 = (const float*)d_in[i]; break;
            case BATCH * HW0 * 4:  reg0 = (const float*)d_in[i]; break;
            case BATCH * HW1 * 4:  reg1 = (const float*)d_in[i]; break;
            case BATCH * HW2 * 4:  reg2 = (const float*)d_in[i]; break;
            case BATCH * NGT * 4:  gt_boxes = (const float*)d_in[i]; break;
            case BATCH * NGT:      gt_labels = (const int*)d_in[i]; break;
            default: break;
        }
    }

    char* ws = (char*)d_ws;
    unsigned int* cnt = (unsigned int*)(ws + CNT_OFF);           // [384]
    unsigned int* done = cnt + NCHUNKS_TOTAL;                    // [1]
    unsigned long long* part = (unsigned long long*)(ws + PART_OFF);
    float* partl = (float*)(ws + PARTL_OFF);

    hipMemsetAsync(cnt, 0, CNT_BYTES, stream);   // 1540 B — tiny DMA node

    mega_kernel<<<GRID, NTH, 0, stream>>>(
        cls0, cls1, cls2, reg0, reg1, reg2, gt_boxes, gt_labels,
        cnt, done, part, partl, (float*)d_out);
}

// Round 9
// 229.108 us; speedup vs baseline: 1.3400x; 1.3400x over previous
//
#include <hip/hip_runtime.h>
#include <cstdint>
#include <cstddef>

#define NTH 256
#define NTH2 1024
#define NGT 128
#define BATCH 16
#define NC 80
#define G 16                  // GTs per scan block
#define NCHUNK (NGT / G)      // 8
#define HW0 25600
#define HW1 6400
#define HW2 1600
#define SL0 8                 // hw slices per level (seg: 3200/3200/1600)
#define SL1 2
#define SL2 1
#define MAXSL 8
#define NB0 (BATCH * NCHUNK * SL0)   // 1024
#define NB1 (BATCH * NCHUNK * SL1)   //  256
#define NB2 (BATCH * NCHUNK * SL2)   //  128
#define SCAN_GRID (NB0 + NB1 + NB2)  // 1408 blocks, all co-resident
#define NLOSS_BLK 96                 // 96 blocks x 16 waves x 4 GTs = 6144

// ws layout (bytes)
#define PART_OFF   0
#define PART_BYTES (3 * BATCH * NGT * MAXSL * 8)           // 393,216
#define PARTL_OFF  PART_BYTES
#define PARTL_BYTES (NLOSS_BLK * 3 * (int)sizeof(float))
#define DONE_OFF   (PARTL_OFF + PARTL_BYTES)

__device__ __forceinline__ unsigned long long umin64(unsigned long long a, unsigned long long b) {
    return a < b ? a : b;
}

#define EVAL(px, py, idx_) do {                                                   \
    _Pragma("unroll")                                                             \
    for (int g = 0; g < G; ++g) {                                                 \
        float dx = gx[g] - (px), dy = gy[g] - (py);                               \
        float d2 = dx * dx + dy * dy;                                             \
        unsigned long long key =                                                  \
            ((unsigned long long)__float_as_uint(d2) << 32) | (unsigned)(idx_);   \
        kmin[g] = umin64(kmin[g], key);                                           \
    } } while (0)

// Scan (R7-identical, fence-free): one block per (level, batch, hw-slice,
// chunk-of-16-GTs), sliced so all 5632 waves are co-resident. u64 key
// (d2 bits << 32 | idx): min == min-d2 with first-index tie-break, exactly
// matching jnp.argmin. Block 0 zeroes the 'done' counter for dispatch 2
// (kernel-boundary release makes it visible — R4-proven pattern).
__global__ __launch_bounds__(NTH) void scan_kernel(
    const float4* __restrict__ reg0, const float4* __restrict__ reg1, const float4* __restrict__ reg2,
    const float* __restrict__ gt_boxes,
    unsigned long long* __restrict__ part, unsigned int* __restrict__ done)
{
    if (blockIdx.x == 0 && threadIdx.x == 0) *done = 0u;

    int x = blockIdx.x;
    int lvl, b, slice, chunk, HW, nsl;
    const float4* src;
    if (x < NB0) {
        lvl = 0; b = x / (NCHUNK * SL0);
        int r = x % (NCHUNK * SL0);
        chunk = r % NCHUNK; slice = r / NCHUNK;
        HW = HW0; nsl = SL0; src = reg0;
    } else if (x < NB0 + NB1) {
        int y = x - NB0;
        lvl = 1; b = y / (NCHUNK * SL1);
        int r = y % (NCHUNK * SL1);
        chunk = r % NCHUNK; slice = r / NCHUNK;
        HW = HW1; nsl = SL1; src = reg1;
    } else {
        int y = x - NB0 - NB1;
        lvl = 2; b = y / NCHUNK; chunk = y % NCHUNK; slice = 0;
        HW = HW2; nsl = SL2; src = reg2;
    }

    const int seg = HW / nsl;
    const int e0 = slice * seg, e1 = e0 + seg;
    const int tid = threadIdx.x, wave = tid >> 6, lane = tid & 63;
    const int n0 = chunk * G;

    float gx[G], gy[G];   // block-uniform -> scalar loads
#pragma unroll
    for (int g = 0; g < G; ++g) {
        const float* gb = gt_boxes + (size_t)(b * NGT + n0 + g) * 4;
        gx[g] = gb[0]; gy[g] = gb[1];
    }

    unsigned long long kmin[G];
#pragma unroll
    for (int g = 0; g < G; ++g) kmin[g] = ~0ull;

    const float4* base = src + (size_t)b * HW;
    for (int i = e0 + tid; i < e1; i += NTH) {
        float4 p = base[i];
        EVAL(p.x, p.y, i);
    }

#pragma unroll
    for (int g = 0; g < G; ++g) {
#pragma unroll
        for (int off = 32; off >= 1; off >>= 1) {
            unsigned long long o = __shfl_down(kmin[g], off, 64);
            kmin[g] = umin64(kmin[g], o);
        }
    }

    __shared__ unsigned long long smem[G][4];
    if (lane == 0) {
#pragma unroll
        for (int g = 0; g < G; ++g) smem[g][wave] = kmin[g];
    }
    __syncthreads();

    if (tid < G) {
        unsigned long long key = umin64(umin64(smem[tid][0], smem[tid][1]),
                                        umin64(smem[tid][2], smem[tid][3]));
        part[((size_t)(lvl * BATCH + b) * NGT + n0 + tid) * MAXSL + slice] = key;
    }
}

// Loss + finalize in ONE dispatch. 96 blocks x 16 waves; wave handles 4
// consecutive GTs. Cascade sized for the R8 lesson (acquires are the
// expensive fence op: ~hundreds of ns each): 96 releases + 96 staggered
// atomicAdds on one counter + exactly ONE acquire in the last block, which
// tree-reduces the 96 partial triples and writes the 3 outputs.
__global__ __launch_bounds__(NTH2) void loss_final_kernel(
    const float* __restrict__ cls0, const float* __restrict__ cls1, const float* __restrict__ cls2,
    const float* __restrict__ reg0, const float* __restrict__ reg1, const float* __restrict__ reg2,
    const float* __restrict__ gt_boxes, const int* __restrict__ gt_labels,
    const unsigned long long* __restrict__ part, float* __restrict__ partl,
    unsigned int* __restrict__ done, float* __restrict__ out)
{
    const int tid = threadIdx.x;
    const int wave = tid >> 6;          // 0..15
    const int lane = tid & 63;
    const int wtask = blockIdx.x * 16 + wave;   // 0..1535
    const int t0 = wtask * 4;                   // first of 4 consecutive GTs
    const int lvl = t0 / (BATCH * NGT);
    const int r = t0 % (BATCH * NGT);
    const int b = r / NGT, nb = r % NGT;        // all 4 GTs share lvl,b

    const float* cls; const float* reg; int HW, S;
    if (lvl == 0)      { cls = cls0; reg = reg0; HW = HW0; S = SL0; }
    else if (lvl == 1) { cls = cls1; reg = reg1; HW = HW1; S = SL1; }
    else               { cls = cls2; reg = reg2; HW = HW2; S = SL2; }

    float ce_acc = 0.0f, l1_acc = 0.0f, w_acc = 0.0f;
#pragma unroll
    for (int j = 0; j < 4; ++j) {
        const int n = nb + j;
        const unsigned long long* p =
            part + ((size_t)(lvl * BATCH + b) * NGT + n) * MAXSL;
        unsigned long long key = p[0];
        for (int s = 1; s < S; ++s) key = umin64(key, p[s]);

        int match = (int)(unsigned)(key & 0xffffffffu);
        float d2min = __uint_as_float((unsigned)(key >> 32));
        if (!(d2min < 6.25f)) continue;         // wave-uniform branch

        const int label = gt_labels[b * NGT + n];
        const float* c = cls + ((size_t)b * HW + match) * NC;

        // 80-class log-softmax: lanes 0..63 hold c[lane], lanes 0..15 also c[64+lane]
        float x1 = c[lane];
        float x2 = (lane < NC - 64) ? c[64 + lane] : -INFINITY;
        float mx = fmaxf(x1, x2);
#pragma unroll
        for (int off = 32; off >= 1; off >>= 1) mx = fmaxf(mx, __shfl_xor(mx, off, 64));
        float s = expf(x1 - mx) + ((lane < NC - 64) ? expf(x2 - mx) : 0.0f);
#pragma unroll
        for (int off = 32; off >= 1; off >>= 1) s += __shfl_xor(s, off, 64);

        if (lane == 0) {
            ce_acc += -(c[label] - mx - logf(s));
            const float* gb = gt_boxes + (size_t)(b * NGT + n) * 4;
            const float* gr = reg + ((size_t)b * HW + match) * 4;
            l1_acc += fabsf(gr[0] - gb[0]) + fabsf(gr[1] - gb[1]) +
                      fabsf(gr[2] - gb[2]) + fabsf(gr[3] - gb[3]);
            w_acc += 1.0f;
        }
    }

    __shared__ float cw[16][3];
    if (lane == 0) { cw[wave][0] = ce_acc; cw[wave][1] = l1_acc; cw[wave][2] = w_acc; }
    __syncthreads();

    __shared__ int is_last;
    if (tid == 0) {
        float ce = 0.0f, l1 = 0.0f, w = 0.0f;
#pragma unroll
        for (int k = 0; k < 16; ++k) { ce += cw[k][0]; l1 += cw[k][1]; w += cw[k][2]; }
        float* o = partl + (size_t)blockIdx.x * 3;
        o[0] = ce; o[1] = l1; o[2] = w;
        __threadfence();                        // release (cheap: ~96 total)
        unsigned int old = atomicAdd(done, 1u); // staggered, one address, 96 adds
        is_last = (old == (unsigned)(NLOSS_BLK - 1));
    }
    __syncthreads();
    if (!is_last) return;

    __threadfence();                            // the ONE acquire
    float ce = 0.0f, l1 = 0.0f, w = 0.0f;
    for (int i = tid; i < NLOSS_BLK; i += NTH2) {   // <=1 element/thread, parallel loads
        ce += partl[(size_t)i * 3 + 0];
        l1 += partl[(size_t)i * 3 + 1];
        w  += partl[(size_t)i * 3 + 2];
    }
#pragma unroll
    for (int off = 32; off >= 1; off >>= 1) {
        ce += __shfl_xor(ce, off, 64);
        l1 += __shfl_xor(l1, off, 64);
        w  += __shfl_xor(w,  off, 64);
    }
    __shared__ float sm[3][16];
    if (lane == 0) { sm[0][wave] = ce; sm[1][wave] = l1; sm[2][wave] = w; }
    __syncthreads();
    if (tid == 0) {
        float tce = 0.0f, tl1 = 0.0f, tw = 0.0f;
#pragma unroll
        for (int k = 0; k < 16; ++k) { tce += sm[0][k]; tl1 += sm[1][k]; tw += sm[2][k]; }
        float denom = fmaxf(tw, 1.0f);
        out[0] = tce / denom;
        out[1] = tl1 / denom;
        out[2] = tw;
    }
}

extern "C" void kernel_launch(void* const* d_in, const int* in_sizes, int n_in,
                              void* d_out, int out_size, void* d_ws, size_t ws_size,
                              hipStream_t stream) {
    // Map inputs BY SIZE (dict order interleaves cls/reg; all sizes distinct).
    const float* cls0 = nullptr; const float* cls1 = nullptr; const float* cls2 = nullptr;
    const float* reg0 = nullptr; const float* reg1 = nullptr; const float* reg2 = nullptr;
    const float* gt_boxes = nullptr; const int* gt_labels = nullptr;
    for (int i = 0; i < n_in; ++i) {
        switch (in_sizes[i]) {
            case BATCH * HW0 * NC: cls0 = (const float*)d_in[i]; break;
            case BATCH * HW1 * NC: cls1 = (const float*)d_in[i]; break;
            case BATCH * HW2 * NC: cls2 = (const float*)d_in[i]; break;
            case BATCH * HW0 * 4:  reg0 = (const float*)d_in[i]; break;
            case BATCH * HW1 * 4:  reg1 = (const float*)d_in[i]; break;
            case BATCH * HW2 * 4:  reg2 = (const float*)d_in[i]; break;
            case BATCH * NGT * 4:  gt_boxes = (const float*)d_in[i]; break;
            case BATCH * NGT:      gt_labels = (const int*)d_in[i]; break;
            default: break;
        }
    }

    char* ws = (char*)d_ws;
    unsigned long long* part = (unsigned long long*)(ws + PART_OFF);
    float* partl = (float*)(ws + PARTL_OFF);
    unsigned int* done = (unsigned int*)(ws + DONE_OFF);

    scan_kernel<<<SCAN_GRID, NTH, 0, stream>>>(
        (const float4*)reg0, (const float4*)reg1, (const float4*)reg2,
        gt_boxes, part, done);

    loss_final_kernel<<<NLOSS_BLK, NTH2, 0, stream>>>(
        cls0, cls1, cls2, reg0, reg1, reg2, gt_boxes, gt_labels,
        part, partl, done, (float*)d_out);
}